// Round 9
// baseline (222.931 us; speedup 1.0000x reference)
//
#include <hip/hip_runtime.h>
#include <math.h>

#define N_NODES 50000
#define N_EDGES 1600000
#define BSH 8                                   // 256 nodes per bucket
#define NBUCK ((N_NODES + 255) >> BSH)          // 196
#define EPB 4096                                // edges per scatter/hist block
#define NBLK ((N_EDGES + EPB - 1) / EPB)        // 391

// ================= CSR build (atomic-free at global scope) =================

__global__ __launch_bounds__(256) void bucket_hist(const int* __restrict__ dst,
                                                   int* __restrict__ bhist_t, int e) {
    __shared__ int h[NBUCK];
    for (int i = threadIdx.x; i < NBUCK; i += 256) h[i] = 0;
    __syncthreads();
    int base = blockIdx.x * EPB;
#pragma unroll
    for (int j = 0; j < EPB / 256; ++j) {
        int i = base + j * 256 + threadIdx.x;
        if (i < e) atomicAdd(&h[dst[i] >> BSH], 1);
    }
    __syncthreads();
    for (int i = threadIdx.x; i < NBUCK; i += 256)
        bhist_t[i * NBLK + blockIdx.x] = h[i];
}

__global__ __launch_bounds__(256) void bucket_totals(const int* __restrict__ bhist_t,
                                                     int* __restrict__ btot) {
    int b = blockIdx.x;
    const int* col = bhist_t + (size_t)b * NBLK;
    int s = 0;
    for (int i = threadIdx.x; i < NBLK; i += 256) s += col[i];
#pragma unroll
    for (int off = 1; off < 64; off <<= 1) s += __shfl_xor(s, off);
    __shared__ int red[4];
    if ((threadIdx.x & 63) == 0) red[threadIdx.x >> 6] = s;
    __syncthreads();
    if (threadIdx.x == 0)
        btot[b] = red[0] + red[1] + red[2] + red[3];
}

__global__ __launch_bounds__(256) void scan_totals(const int* __restrict__ btot,
                                                   int* __restrict__ bbase,
                                                   int* __restrict__ rowptr) {
    __shared__ int s[256];
    int b = threadIdx.x;
    int v = (b < NBUCK) ? btot[b] : 0;
    s[b] = v;
    __syncthreads();
    for (int off = 1; off < 256; off <<= 1) {
        int t = (b >= off) ? s[b - off] : 0;
        __syncthreads();
        s[b] += t;
        __syncthreads();
    }
    if (b < NBUCK) bbase[b] = s[b] - v;
    if (b == NBUCK - 1) { bbase[NBUCK] = s[b]; rowptr[N_NODES] = s[b]; }
}

__global__ __launch_bounds__(64) void rewrite_offsets(int* __restrict__ bhist_t,
                                                      const int* __restrict__ bbase) {
    int b = blockIdx.x;
    int* col = bhist_t + (size_t)b * NBLK;
    __shared__ int buf[NBLK];
    for (int i = threadIdx.x; i < NBLK; i += 64) buf[i] = col[i];
    __syncthreads();
    constexpr int CH = (NBLK + 63) / 64;
    int lane = threadIdx.x;
    int lo = lane * CH;
    int hi = lo + CH; if (hi > NBLK) hi = NBLK;
    int s = 0;
    for (int i = lo; i < hi; ++i) s += buf[i];
    int inc = s;
#pragma unroll
    for (int off = 1; off < 64; off <<= 1) {
        int t = __shfl_up(inc, off);
        if (lane >= off) inc += t;
    }
    int run = bbase[b] + inc - s;
    for (int i = lo; i < hi; ++i) { int c = buf[i]; col[i] = run; run += c; }
}

__global__ __launch_bounds__(256) void bucket_scatter(const int* __restrict__ src,
                                                      const int* __restrict__ dst,
                                                      const int* __restrict__ bhist_t,
                                                      unsigned* __restrict__ packed, int e) {
    __shared__ int lcur[NBUCK];
    int r = blockIdx.x;
    for (int i = threadIdx.x; i < NBUCK; i += 256)
        lcur[i] = bhist_t[i * NBLK + r];
    __syncthreads();
    int base = r * EPB;
#pragma unroll
    for (int j = 0; j < EPB / 256; ++j) {
        int i = base + j * 256 + threadIdx.x;
        if (i < e) {
            int d = dst[i];
            int pos = atomicAdd(&lcur[d >> BSH], 1);
            packed[pos] = (unsigned)src[i] | ((unsigned)(d & ((1 << BSH) - 1)) << 16);
        }
    }
}

__global__ __launch_bounds__(512) void csr_finalize(const unsigned* __restrict__ packed,
                                                    const int* __restrict__ bbase,
                                                    int* __restrict__ rowptr,
                                                    int* __restrict__ csr_src) {
    int b = blockIdx.x;
    int s0 = bbase[b], s1 = bbase[b + 1];
    int cnt = s1 - s0;
    __shared__ int ncnt[256];
    __shared__ int ncur[256];
    __shared__ int wsum[4];
    if (threadIdx.x < 256) ncnt[threadIdx.x] = 0;
    __syncthreads();
    for (int i = threadIdx.x; i < cnt; i += 512)
        atomicAdd(&ncnt[packed[s0 + i] >> 16], 1);
    __syncthreads();
    int lane = threadIdx.x & 63, w = threadIdx.x >> 6;
    int v = 0, inc = 0;
    if (threadIdx.x < 256) {
        v = ncnt[threadIdx.x]; inc = v;
#pragma unroll
        for (int off = 1; off < 64; off <<= 1) {
            int t = __shfl_up(inc, off);
            if (lane >= off) inc += t;
        }
        if (lane == 63) wsum[w] = inc;
    }
    __syncthreads();
    if (threadIdx.x < 256) {
        int woff = 0;
#pragma unroll
        for (int k = 0; k < 3; ++k) if (k < w) woff += wsum[k];
        int excl = woff + inc - v;
        int node = (b << BSH) + threadIdx.x;
        if (node < N_NODES) rowptr[node] = s0 + excl;
        ncur[threadIdx.x] = s0 + excl;
    }
    __syncthreads();
    for (int i = threadIdx.x; i < cnt; i += 512) {
        unsigned p = packed[s0 + i];
        int pos = atomicAdd(&ncur[p >> 16], 1);
        csr_src[pos] = (int)(p & 0xFFFFu);
    }
}

// ================= register-tiled GEMM + fused alpha =================

template<int K, int C>
__global__ __launch_bounds__(256) void gemm_alpha(
        const float* __restrict__ in, const float* __restrict__ W,
        const float* __restrict__ a_src, const float* __restrict__ a_dst,
        float* __restrict__ h, float* __restrict__ as_, float* __restrict__ ad_, int n)
{
    constexpr int CPT = C / 16;
    constexpr int KP = K + 4;
    __shared__ float sx[64][KP];
    __shared__ float sW[K * C];
    int row0 = blockIdx.x * 64;
    int nvalid = n - row0;

    for (int idx = threadIdx.x; idx < 64 * K / 4; idx += 256) {
        int r = idx / (K / 4), kc = idx % (K / 4);
        float4 v = {0, 0, 0, 0};
        if (r < nvalid) v = *(const float4*)&in[(size_t)(row0 + r) * K + kc * 4];
        *(float4*)&sx[r][kc * 4] = v;
    }
    for (int idx = threadIdx.x; idx < K * C / 4; idx += 256)
        *(float4*)&sW[idx * 4] = *(const float4*)&W[idx * 4];
    __syncthreads();

    int g  = threadIdx.x >> 4;
    int ci = threadIdx.x & 15;
    int r0 = g * 4;
    int c0 = ci * CPT;

    if constexpr (CPT == 4) {
        float4 acc0 = {0,0,0,0}, acc1 = {0,0,0,0}, acc2 = {0,0,0,0}, acc3 = {0,0,0,0};
        for (int k = 0; k < K; k += 4) {
            float4 w0 = *(const float4*)&sW[(k + 0) * C + c0];
            float4 w1 = *(const float4*)&sW[(k + 1) * C + c0];
            float4 w2 = *(const float4*)&sW[(k + 2) * C + c0];
            float4 w3 = *(const float4*)&sW[(k + 3) * C + c0];
            float4 x0 = *(const float4*)&sx[r0 + 0][k];
            float4 x1 = *(const float4*)&sx[r0 + 1][k];
            float4 x2 = *(const float4*)&sx[r0 + 2][k];
            float4 x3 = *(const float4*)&sx[r0 + 3][k];
#define STEP(A, X) \
            A.x = fmaf(X.x, w0.x, A.x); A.y = fmaf(X.x, w0.y, A.y); \
            A.z = fmaf(X.x, w0.z, A.z); A.w = fmaf(X.x, w0.w, A.w); \
            A.x = fmaf(X.y, w1.x, A.x); A.y = fmaf(X.y, w1.y, A.y); \
            A.z = fmaf(X.y, w1.z, A.z); A.w = fmaf(X.y, w1.w, A.w); \
            A.x = fmaf(X.z, w2.x, A.x); A.y = fmaf(X.z, w2.y, A.y); \
            A.z = fmaf(X.z, w2.z, A.z); A.w = fmaf(X.z, w2.w, A.w); \
            A.x = fmaf(X.w, w3.x, A.x); A.y = fmaf(X.w, w3.y, A.y); \
            A.z = fmaf(X.w, w3.z, A.z); A.w = fmaf(X.w, w3.w, A.w);
            STEP(acc0, x0) STEP(acc1, x1) STEP(acc2, x2) STEP(acc3, x3)
#undef STEP
        }
        if (r0 + 0 < nvalid) *(float4*)&h[(size_t)(row0 + r0 + 0) * C + c0] = acc0;
        if (r0 + 1 < nvalid) *(float4*)&h[(size_t)(row0 + r0 + 1) * C + c0] = acc1;
        if (r0 + 2 < nvalid) *(float4*)&h[(size_t)(row0 + r0 + 2) * C + c0] = acc2;
        if (r0 + 3 < nvalid) *(float4*)&h[(size_t)(row0 + r0 + 3) * C + c0] = acc3;
        float4 asv = *(const float4*)&a_src[c0];
        float4 adv = *(const float4*)&a_dst[c0];
        float vs0 = acc0.x*asv.x + acc0.y*asv.y + acc0.z*asv.z + acc0.w*asv.w;
        float vs1 = acc1.x*asv.x + acc1.y*asv.y + acc1.z*asv.z + acc1.w*asv.w;
        float vs2 = acc2.x*asv.x + acc2.y*asv.y + acc2.z*asv.z + acc2.w*asv.w;
        float vs3 = acc3.x*asv.x + acc3.y*asv.y + acc3.z*asv.z + acc3.w*asv.w;
        float vd0 = acc0.x*adv.x + acc0.y*adv.y + acc0.z*adv.z + acc0.w*adv.w;
        float vd1 = acc1.x*adv.x + acc1.y*adv.y + acc1.z*adv.z + acc1.w*adv.w;
        float vd2 = acc2.x*adv.x + acc2.y*adv.y + acc2.z*adv.z + acc2.w*adv.w;
        float vd3 = acc3.x*adv.x + acc3.y*adv.y + acc3.z*adv.z + acc3.w*adv.w;
#pragma unroll
        for (int off = 1; off < 16; off <<= 1) {
            vs0 += __shfl_xor(vs0, off); vs1 += __shfl_xor(vs1, off);
            vs2 += __shfl_xor(vs2, off); vs3 += __shfl_xor(vs3, off);
            vd0 += __shfl_xor(vd0, off); vd1 += __shfl_xor(vd1, off);
            vd2 += __shfl_xor(vd2, off); vd3 += __shfl_xor(vd3, off);
        }
        if (ci == 0) {
            if (r0 + 0 < nvalid) { as_[row0+r0+0] = vs0; ad_[row0+r0+0] = vd0; }
            if (r0 + 1 < nvalid) { as_[row0+r0+1] = vs1; ad_[row0+r0+1] = vd1; }
            if (r0 + 2 < nvalid) { as_[row0+r0+2] = vs2; ad_[row0+r0+2] = vd2; }
            if (r0 + 3 < nvalid) { as_[row0+r0+3] = vs3; ad_[row0+r0+3] = vd3; }
        }
    } else {                               // CPT == 1  (C = 16)
        float s0 = 0.f, s1 = 0.f, s2 = 0.f, s3 = 0.f;
        for (int k = 0; k < K; k += 4) {
            float w0 = sW[(k + 0) * C + c0];
            float w1 = sW[(k + 1) * C + c0];
            float w2 = sW[(k + 2) * C + c0];
            float w3 = sW[(k + 3) * C + c0];
            float4 x0 = *(const float4*)&sx[r0 + 0][k];
            float4 x1 = *(const float4*)&sx[r0 + 1][k];
            float4 x2 = *(const float4*)&sx[r0 + 2][k];
            float4 x3 = *(const float4*)&sx[r0 + 3][k];
            s0 = fmaf(x0.x,w0, fmaf(x0.y,w1, fmaf(x0.z,w2, fmaf(x0.w,w3, s0))));
            s1 = fmaf(x1.x,w0, fmaf(x1.y,w1, fmaf(x1.z,w2, fmaf(x1.w,w3, s1))));
            s2 = fmaf(x2.x,w0, fmaf(x2.y,w1, fmaf(x2.z,w2, fmaf(x2.w,w3, s2))));
            s3 = fmaf(x3.x,w0, fmaf(x3.y,w1, fmaf(x3.z,w2, fmaf(x3.w,w3, s3))));
        }
        if (r0 + 0 < nvalid) h[(size_t)(row0+r0+0) * C + c0] = s0;
        if (r0 + 1 < nvalid) h[(size_t)(row0+r0+1) * C + c0] = s1;
        if (r0 + 2 < nvalid) h[(size_t)(row0+r0+2) * C + c0] = s2;
        if (r0 + 3 < nvalid) h[(size_t)(row0+r0+3) * C + c0] = s3;
        float as0 = a_src[c0], ad0 = a_dst[c0];
        float vs0 = s0*as0, vs1 = s1*as0, vs2 = s2*as0, vs3 = s3*as0;
        float vd0 = s0*ad0, vd1 = s1*ad0, vd2 = s2*ad0, vd3 = s3*ad0;
#pragma unroll
        for (int off = 1; off < 16; off <<= 1) {
            vs0 += __shfl_xor(vs0, off); vs1 += __shfl_xor(vs1, off);
            vs2 += __shfl_xor(vs2, off); vs3 += __shfl_xor(vs3, off);
            vd0 += __shfl_xor(vd0, off); vd1 += __shfl_xor(vd1, off);
            vd2 += __shfl_xor(vd2, off); vd3 += __shfl_xor(vd3, off);
        }
        if (ci == 0) {
            if (r0 + 0 < nvalid) { as_[row0+r0+0] = vs0; ad_[row0+r0+0] = vd0; }
            if (r0 + 1 < nvalid) { as_[row0+r0+1] = vs1; ad_[row0+r0+1] = vd1; }
            if (r0 + 2 < nvalid) { as_[row0+r0+2] = vs2; ad_[row0+r0+2] = vd2; }
            if (r0 + 3 < nvalid) { as_[row0+r0+3] = vs3; ad_[row0+r0+3] = vd3; }
        }
    }
}

// ================= fused single-pass softmax + aggregation =================
// Cooperative alpha (1 exp/edge, coalesced), shfl-distributed; 8 gathers in
// flight per wave (latency-bound fix). All shfls exec-uniform: gather bound
// nvu is a multiple of the 32-slot stripe so every group runs identical trips.

__device__ __forceinline__ float leaky(float e) {
    return (e >= 0.f) ? e : 0.2f * e;
}

template<bool RELU>
__global__ __launch_bounds__(256) void agg64(
        const float* __restrict__ h, const float* __restrict__ as_, const float* __restrict__ ad_,
        const int* __restrict__ rowptr, const int* __restrict__ csr_src,
        const float* __restrict__ bias, float* __restrict__ out, int n)
{
    int node = (blockIdx.x * blockDim.x + threadIdx.x) >> 6;
    if (node >= n) return;
    int lane = threadIdx.x & 63;
    int g  = lane >> 4;       // edge group 0..3 (handles slots j = g+4k)
    int c4 = lane & 15;       // float4 slot within 64-ch row
    int start = rowptr[node], end = rowptr[node + 1];
    float adn = ad_[node];
    const char* hb = (const char*)h + (size_t)c4 * 16;   // h + c4*4 floats

    float4 acc = {0,0,0,0};
    float dsum = 0.f;

    for (int chunk = start; chunk < end; chunk += 64) {
        int e_i = chunk + lane;
        int soff = 0; float aw = 0.f;
        if (e_i < end) {
            int ssrc = csr_src[e_i];                   // coalesced
            soff = ssrc << 8;                          // byte offset of h row
            aw = __expf(leaky(as_[ssrc] + adn));       // 1 exp per edge
        }
        dsum += aw;                                    // denom: butterfly later
        int nv = end - chunk; if (nv > 64) nv = 64;
        int nvu = (nv + 31) & ~31;                     // stripes of 32 slots
        for (int j = g; j < nvu; j += 32) {            // 8 gathers in flight
            int   o0 = __shfl(soff, j),      o1 = __shfl(soff, j + 4);
            int   o2 = __shfl(soff, j + 8),  o3 = __shfl(soff, j + 12);
            int   o4 = __shfl(soff, j + 16), o5 = __shfl(soff, j + 20);
            int   o6 = __shfl(soff, j + 24), o7 = __shfl(soff, j + 28);
            float w0 = __shfl(aw, j),        w1 = __shfl(aw, j + 4);
            float w2 = __shfl(aw, j + 8),    w3 = __shfl(aw, j + 12);
            float w4 = __shfl(aw, j + 16),   w5 = __shfl(aw, j + 20);
            float w6 = __shfl(aw, j + 24),   w7 = __shfl(aw, j + 28);
            float4 h0 = *(const float4*)(hb + o0);
            float4 h1 = *(const float4*)(hb + o1);
            float4 h2 = *(const float4*)(hb + o2);
            float4 h3 = *(const float4*)(hb + o3);
            float4 h4 = *(const float4*)(hb + o4);
            float4 h5 = *(const float4*)(hb + o5);
            float4 h6 = *(const float4*)(hb + o6);
            float4 h7 = *(const float4*)(hb + o7);
            acc.x = fmaf(w0, h0.x, acc.x); acc.y = fmaf(w0, h0.y, acc.y);
            acc.z = fmaf(w0, h0.z, acc.z); acc.w = fmaf(w0, h0.w, acc.w);
            acc.x = fmaf(w1, h1.x, acc.x); acc.y = fmaf(w1, h1.y, acc.y);
            acc.z = fmaf(w1, h1.z, acc.z); acc.w = fmaf(w1, h1.w, acc.w);
            acc.x = fmaf(w2, h2.x, acc.x); acc.y = fmaf(w2, h2.y, acc.y);
            acc.z = fmaf(w2, h2.z, acc.z); acc.w = fmaf(w2, h2.w, acc.w);
            acc.x = fmaf(w3, h3.x, acc.x); acc.y = fmaf(w3, h3.y, acc.y);
            acc.z = fmaf(w3, h3.z, acc.z); acc.w = fmaf(w3, h3.w, acc.w);
            acc.x = fmaf(w4, h4.x, acc.x); acc.y = fmaf(w4, h4.y, acc.y);
            acc.z = fmaf(w4, h4.z, acc.z); acc.w = fmaf(w4, h4.w, acc.w);
            acc.x = fmaf(w5, h5.x, acc.x); acc.y = fmaf(w5, h5.y, acc.y);
            acc.z = fmaf(w5, h5.z, acc.z); acc.w = fmaf(w5, h5.w, acc.w);
            acc.x = fmaf(w6, h6.x, acc.x); acc.y = fmaf(w6, h6.y, acc.y);
            acc.z = fmaf(w6, h6.z, acc.z); acc.w = fmaf(w6, h6.w, acc.w);
            acc.x = fmaf(w7, h7.x, acc.x); acc.y = fmaf(w7, h7.y, acc.y);
            acc.z = fmaf(w7, h7.z, acc.z); acc.w = fmaf(w7, h7.w, acc.w);
        }
    }
    // combine the 4 edge groups (all lanes active)
#pragma unroll
    for (int off = 16; off <= 32; off <<= 1) {
        acc.x += __shfl_xor(acc.x, off); acc.y += __shfl_xor(acc.y, off);
        acc.z += __shfl_xor(acc.z, off); acc.w += __shfl_xor(acc.w, off);
    }
    // full-wave denom reduction
#pragma unroll
    for (int off = 1; off <= 32; off <<= 1) dsum += __shfl_xor(dsum, off);

    if (g == 0) {
        float inv = 1.f / (dsum + 1e-16f);
        float4 bv = *(const float4*)&bias[c4 * 4];
        float4 o;
        o.x = fmaf(acc.x, inv, bv.x); o.y = fmaf(acc.y, inv, bv.y);
        o.z = fmaf(acc.z, inv, bv.z); o.w = fmaf(acc.w, inv, bv.w);
        if (RELU) {
            o.x = fmaxf(o.x, 0.f); o.y = fmaxf(o.y, 0.f);
            o.z = fmaxf(o.z, 0.f); o.w = fmaxf(o.w, 0.f);
        }
        *(float4*)&out[(size_t)node * 64 + c4 * 4] = o;
    }
}

template<bool RELU>
__global__ __launch_bounds__(256) void agg16(
        const float* __restrict__ h, const float* __restrict__ as_, const float* __restrict__ ad_,
        const int* __restrict__ rowptr, const int* __restrict__ csr_src,
        const float* __restrict__ bias, float* __restrict__ out, int n)
{
    int node = (blockIdx.x * blockDim.x + threadIdx.x) >> 6;
    if (node >= n) return;
    int lane = threadIdx.x & 63;
    int g  = lane >> 2;       // edge group 0..15 (handles slots j = g+16k)
    int c4 = lane & 3;        // float4 slot within 16-ch row
    int start = rowptr[node], end = rowptr[node + 1];
    float adn = ad_[node];
    const char* hb = (const char*)h + (size_t)c4 * 16;

    float4 acc = {0,0,0,0};
    float dsum = 0.f;

    for (int chunk = start; chunk < end; chunk += 64) {
        int e_i = chunk + lane;
        int soff = 0; float aw = 0.f;
        if (e_i < end) {
            int ssrc = csr_src[e_i];
            soff = ssrc << 6;                          // byte offset (16 floats)
            aw = __expf(leaky(as_[ssrc] + adn));
        }
        dsum += aw;
        int nv = end - chunk; if (nv > 64) nv = 64;
        int nvu = (nv + 31) & ~31;                     // stripes of 32 slots
        for (int j = g; j < nvu; j += 32) {            // 2 gathers in flight
            int   o0 = __shfl(soff, j);
            int   o1 = __shfl(soff, j + 16);
            float w0 = __shfl(aw, j);
            float w1 = __shfl(aw, j + 16);
            float4 h0 = *(const float4*)(hb + o0);
            float4 h1 = *(const float4*)(hb + o1);
            acc.x = fmaf(w0, h0.x, acc.x); acc.y = fmaf(w0, h0.y, acc.y);
            acc.z = fmaf(w0, h0.z, acc.z); acc.w = fmaf(w0, h0.w, acc.w);
            acc.x = fmaf(w1, h1.x, acc.x); acc.y = fmaf(w1, h1.y, acc.y);
            acc.z = fmaf(w1, h1.z, acc.z); acc.w = fmaf(w1, h1.w, acc.w);
        }
    }
#pragma unroll
    for (int off = 4; off <= 32; off <<= 1) {
        acc.x += __shfl_xor(acc.x, off); acc.y += __shfl_xor(acc.y, off);
        acc.z += __shfl_xor(acc.z, off); acc.w += __shfl_xor(acc.w, off);
    }
#pragma unroll
    for (int off = 1; off <= 32; off <<= 1) dsum += __shfl_xor(dsum, off);

    if (g == 0) {
        float inv = 1.f / (dsum + 1e-16f);
        float4 bv = *(const float4*)&bias[c4 * 4];
        float4 o;
        o.x = fmaf(acc.x, inv, bv.x); o.y = fmaf(acc.y, inv, bv.y);
        o.z = fmaf(acc.z, inv, bv.z); o.w = fmaf(acc.w, inv, bv.w);
        if (RELU) {
            o.x = fmaxf(o.x, 0.f); o.y = fmaxf(o.y, 0.f);
            o.z = fmaxf(o.z, 0.f); o.w = fmaxf(o.w, 0.f);
        }
        *(float4*)&out[(size_t)node * 16 + c4 * 4] = o;
    }
}

// ================= launch =================

extern "C" void kernel_launch(void* const* d_in, const int* in_sizes, int n_in,
                              void* d_out, int out_size, void* d_ws, size_t ws_size,
                              hipStream_t stream) {
    const float* x   = (const float*)d_in[0];
    const int*   ei  = (const int*)  d_in[1];
    const float* W1  = (const float*)d_in[3];
    const float* as1 = (const float*)d_in[4];
    const float* ad1 = (const float*)d_in[5];
    const float* b1  = (const float*)d_in[6];
    const float* W2  = (const float*)d_in[7];
    const float* as2 = (const float*)d_in[8];
    const float* ad2 = (const float*)d_in[9];
    const float* b2  = (const float*)d_in[10];
    const float* W3  = (const float*)d_in[11];
    const float* as3 = (const float*)d_in[12];
    const float* ad3 = (const float*)d_in[13];
    const float* b3  = (const float*)d_in[14];

    const int* srcp = ei;
    const int* dstp = ei + N_EDGES;

    char* ws = (char*)d_ws;
    size_t off = 0;
    auto alloc = [&](size_t bytes) -> void* {
        void* p = ws + off;
        off = (off + bytes + 255) & ~(size_t)255;
        return p;
    };
    int*   bhist_t = (int*)  alloc((size_t)NBUCK * NBLK * sizeof(int));
    int*   btot    = (int*)  alloc(NBUCK * sizeof(int));
    int*   bbase   = (int*)  alloc((NBUCK + 1) * sizeof(int));
    int*   rowptr  = (int*)  alloc((N_NODES + 1) * sizeof(int));
    int*   csr_src = (int*)  alloc(N_EDGES * sizeof(int));
    float* asb     = (float*)alloc(N_NODES * sizeof(float));
    float* adb     = (float*)alloc(N_NODES * sizeof(float));
    float* bufA    = (float*)alloc((size_t)N_NODES * 64 * sizeof(float));
    float* bufB    = (float*)alloc((size_t)N_NODES * 64 * sizeof(float));
    unsigned* packed = (unsigned*)bufA;   // dead before agg1 writes bufA

    bucket_hist    <<<NBLK,  256, 0, stream>>>(dstp, bhist_t, N_EDGES);
    bucket_totals  <<<NBUCK, 256, 0, stream>>>(bhist_t, btot);
    scan_totals    <<<1,     256, 0, stream>>>(btot, bbase, rowptr);
    rewrite_offsets<<<NBUCK, 64,  0, stream>>>(bhist_t, bbase);
    bucket_scatter <<<NBLK,  256, 0, stream>>>(srcp, dstp, bhist_t, packed, N_EDGES);
    csr_finalize   <<<NBUCK, 512, 0, stream>>>(packed, bbase, rowptr, csr_src);

    const int NB64 = (N_NODES + 63) / 64;
    const int NB4  = (N_NODES + 3) / 4;

    // layer 1: 128 -> 64, relu
    gemm_alpha<128, 64><<<NB64, 256, 0, stream>>>(x, W1, as1, ad1, bufB, asb, adb, N_NODES);
    agg64<true><<<NB4, 256, 0, stream>>>(bufB, asb, adb, rowptr, csr_src, b1, bufA, N_NODES);

    // layer 2: 64 -> 64, relu
    gemm_alpha<64, 64><<<NB64, 256, 0, stream>>>(bufA, W2, as2, ad2, bufB, asb, adb, N_NODES);
    agg64<true><<<NB4, 256, 0, stream>>>(bufB, asb, adb, rowptr, csr_src, b2, bufA, N_NODES);

    // layer 3: 64 -> 16, no relu
    gemm_alpha<64, 16><<<NB64, 256, 0, stream>>>(bufA, W3, as3, ad3, bufB, asb, adb, N_NODES);
    agg16<false><<<NB4, 256, 0, stream>>>(bufB, asb, adb, rowptr, csr_src, b3, (float*)d_out, N_NODES);
}

// Round 10
// 185.271 us; speedup vs baseline: 1.2033x; 1.2033x over previous
//
#include <hip/hip_runtime.h>
#include <hip/hip_fp16.h>
#include <math.h>

#define N_NODES 50000
#define N_EDGES 1600000
#define BSH 8                                   // 256 nodes per bucket
#define NBUCK ((N_NODES + 255) >> BSH)          // 196
#define EPB 4096                                // edges per scatter/hist block
#define NBLK ((N_EDGES + EPB - 1) / EPB)        // 391

// ================= CSR build (atomic-free at global scope) =================

__global__ __launch_bounds__(256) void bucket_hist(const int* __restrict__ dst,
                                                   int* __restrict__ bhist_t, int e) {
    __shared__ int h[NBUCK];
    for (int i = threadIdx.x; i < NBUCK; i += 256) h[i] = 0;
    __syncthreads();
    int base = blockIdx.x * EPB;
#pragma unroll
    for (int j = 0; j < EPB / 256; ++j) {
        int i = base + j * 256 + threadIdx.x;
        if (i < e) atomicAdd(&h[dst[i] >> BSH], 1);
    }
    __syncthreads();
    for (int i = threadIdx.x; i < NBUCK; i += 256)
        bhist_t[i * NBLK + blockIdx.x] = h[i];
}

__global__ __launch_bounds__(256) void bucket_totals(const int* __restrict__ bhist_t,
                                                     int* __restrict__ btot) {
    int b = blockIdx.x;
    const int* col = bhist_t + (size_t)b * NBLK;
    int s = 0;
    for (int i = threadIdx.x; i < NBLK; i += 256) s += col[i];
#pragma unroll
    for (int off = 1; off < 64; off <<= 1) s += __shfl_xor(s, off);
    __shared__ int red[4];
    if ((threadIdx.x & 63) == 0) red[threadIdx.x >> 6] = s;
    __syncthreads();
    if (threadIdx.x == 0)
        btot[b] = red[0] + red[1] + red[2] + red[3];
}

__global__ __launch_bounds__(256) void scan_totals(const int* __restrict__ btot,
                                                   int* __restrict__ bbase,
                                                   int* __restrict__ rowptr) {
    __shared__ int s[256];
    int b = threadIdx.x;
    int v = (b < NBUCK) ? btot[b] : 0;
    s[b] = v;
    __syncthreads();
    for (int off = 1; off < 256; off <<= 1) {
        int t = (b >= off) ? s[b - off] : 0;
        __syncthreads();
        s[b] += t;
        __syncthreads();
    }
    if (b < NBUCK) bbase[b] = s[b] - v;
    if (b == NBUCK - 1) { bbase[NBUCK] = s[b]; rowptr[N_NODES] = s[b]; }
}

__global__ __launch_bounds__(64) void rewrite_offsets(int* __restrict__ bhist_t,
                                                      const int* __restrict__ bbase) {
    int b = blockIdx.x;
    int* col = bhist_t + (size_t)b * NBLK;
    __shared__ int buf[NBLK];
    for (int i = threadIdx.x; i < NBLK; i += 64) buf[i] = col[i];
    __syncthreads();
    constexpr int CH = (NBLK + 63) / 64;
    int lane = threadIdx.x;
    int lo = lane * CH;
    int hi = lo + CH; if (hi > NBLK) hi = NBLK;
    int s = 0;
    for (int i = lo; i < hi; ++i) s += buf[i];
    int inc = s;
#pragma unroll
    for (int off = 1; off < 64; off <<= 1) {
        int t = __shfl_up(inc, off);
        if (lane >= off) inc += t;
    }
    int run = bbase[b] + inc - s;
    for (int i = lo; i < hi; ++i) { int c = buf[i]; col[i] = run; run += c; }
}

__global__ __launch_bounds__(256) void bucket_scatter(const int* __restrict__ src,
                                                      const int* __restrict__ dst,
                                                      const int* __restrict__ bhist_t,
                                                      unsigned* __restrict__ packed, int e) {
    __shared__ int lcur[NBUCK];
    int r = blockIdx.x;
    for (int i = threadIdx.x; i < NBUCK; i += 256)
        lcur[i] = bhist_t[i * NBLK + r];
    __syncthreads();
    int base = r * EPB;
#pragma unroll
    for (int j = 0; j < EPB / 256; ++j) {
        int i = base + j * 256 + threadIdx.x;
        if (i < e) {
            int d = dst[i];
            int pos = atomicAdd(&lcur[d >> BSH], 1);
            packed[pos] = (unsigned)src[i] | ((unsigned)(d & ((1 << BSH) - 1)) << 16);
        }
    }
}

__global__ __launch_bounds__(512) void csr_finalize(const unsigned* __restrict__ packed,
                                                    const int* __restrict__ bbase,
                                                    int* __restrict__ rowptr,
                                                    int* __restrict__ csr_src) {
    int b = blockIdx.x;
    int s0 = bbase[b], s1 = bbase[b + 1];
    int cnt = s1 - s0;
    __shared__ int ncnt[256];
    __shared__ int ncur[256];
    __shared__ int wsum[4];
    if (threadIdx.x < 256) ncnt[threadIdx.x] = 0;
    __syncthreads();
    for (int i = threadIdx.x; i < cnt; i += 512)
        atomicAdd(&ncnt[packed[s0 + i] >> 16], 1);
    __syncthreads();
    int lane = threadIdx.x & 63, w = threadIdx.x >> 6;
    int v = 0, inc = 0;
    if (threadIdx.x < 256) {
        v = ncnt[threadIdx.x]; inc = v;
#pragma unroll
        for (int off = 1; off < 64; off <<= 1) {
            int t = __shfl_up(inc, off);
            if (lane >= off) inc += t;
        }
        if (lane == 63) wsum[w] = inc;
    }
    __syncthreads();
    if (threadIdx.x < 256) {
        int woff = 0;
#pragma unroll
        for (int k = 0; k < 3; ++k) if (k < w) woff += wsum[k];
        int excl = woff + inc - v;
        int node = (b << BSH) + threadIdx.x;
        if (node < N_NODES) rowptr[node] = s0 + excl;
        ncur[threadIdx.x] = s0 + excl;
    }
    __syncthreads();
    for (int i = threadIdx.x; i < cnt; i += 512) {
        unsigned p = packed[s0 + i];
        int pos = atomicAdd(&ncur[p >> 16], 1);
        csr_src[pos] = (int)(p & 0xFFFFu);
    }
}

// ================= register-tiled GEMM + fused alpha =================
// HALF_OUT: store h as fp16 (the agg gather payload); accumulation, as_/ad_
// remain fp32 so only the gathered table is quantized.

template<int K, int C, bool HALF_OUT>
__global__ __launch_bounds__(256) void gemm_alpha(
        const float* __restrict__ in, const float* __restrict__ W,
        const float* __restrict__ a_src, const float* __restrict__ a_dst,
        void* __restrict__ hv, float* __restrict__ as_, float* __restrict__ ad_, int n)
{
    constexpr int CPT = C / 16;
    constexpr int KP = K + 4;
    __shared__ float sx[64][KP];
    __shared__ float sW[K * C];
    int row0 = blockIdx.x * 64;
    int nvalid = n - row0;

    for (int idx = threadIdx.x; idx < 64 * K / 4; idx += 256) {
        int r = idx / (K / 4), kc = idx % (K / 4);
        float4 v = {0, 0, 0, 0};
        if (r < nvalid) v = *(const float4*)&in[(size_t)(row0 + r) * K + kc * 4];
        *(float4*)&sx[r][kc * 4] = v;
    }
    for (int idx = threadIdx.x; idx < K * C / 4; idx += 256)
        *(float4*)&sW[idx * 4] = *(const float4*)&W[idx * 4];
    __syncthreads();

    int g  = threadIdx.x >> 4;
    int ci = threadIdx.x & 15;
    int r0 = g * 4;
    int c0 = ci * CPT;

    if constexpr (CPT == 4) {
        float4 acc0 = {0,0,0,0}, acc1 = {0,0,0,0}, acc2 = {0,0,0,0}, acc3 = {0,0,0,0};
        for (int k = 0; k < K; k += 4) {
            float4 w0 = *(const float4*)&sW[(k + 0) * C + c0];
            float4 w1 = *(const float4*)&sW[(k + 1) * C + c0];
            float4 w2 = *(const float4*)&sW[(k + 2) * C + c0];
            float4 w3 = *(const float4*)&sW[(k + 3) * C + c0];
            float4 x0 = *(const float4*)&sx[r0 + 0][k];
            float4 x1 = *(const float4*)&sx[r0 + 1][k];
            float4 x2 = *(const float4*)&sx[r0 + 2][k];
            float4 x3 = *(const float4*)&sx[r0 + 3][k];
#define STEP(A, X) \
            A.x = fmaf(X.x, w0.x, A.x); A.y = fmaf(X.x, w0.y, A.y); \
            A.z = fmaf(X.x, w0.z, A.z); A.w = fmaf(X.x, w0.w, A.w); \
            A.x = fmaf(X.y, w1.x, A.x); A.y = fmaf(X.y, w1.y, A.y); \
            A.z = fmaf(X.y, w1.z, A.z); A.w = fmaf(X.y, w1.w, A.w); \
            A.x = fmaf(X.z, w2.x, A.x); A.y = fmaf(X.z, w2.y, A.y); \
            A.z = fmaf(X.z, w2.z, A.z); A.w = fmaf(X.z, w2.w, A.w); \
            A.x = fmaf(X.w, w3.x, A.x); A.y = fmaf(X.w, w3.y, A.y); \
            A.z = fmaf(X.w, w3.z, A.z); A.w = fmaf(X.w, w3.w, A.w);
            STEP(acc0, x0) STEP(acc1, x1) STEP(acc2, x2) STEP(acc3, x3)
#undef STEP
        }
        if constexpr (HALF_OUT) {
            __half* hh = (__half*)hv;
            auto sth = [&](int r, float4 a) {
                if (r0 + r < nvalid) {
                    size_t base = (size_t)(row0 + r0 + r) * C + c0;
                    *(__half2*)&hh[base]     = __floats2half2_rn(a.x, a.y);
                    *(__half2*)&hh[base + 2] = __floats2half2_rn(a.z, a.w);
                }
            };
            sth(0, acc0); sth(1, acc1); sth(2, acc2); sth(3, acc3);
        } else {
            float* h = (float*)hv;
            if (r0 + 0 < nvalid) *(float4*)&h[(size_t)(row0 + r0 + 0) * C + c0] = acc0;
            if (r0 + 1 < nvalid) *(float4*)&h[(size_t)(row0 + r0 + 1) * C + c0] = acc1;
            if (r0 + 2 < nvalid) *(float4*)&h[(size_t)(row0 + r0 + 2) * C + c0] = acc2;
            if (r0 + 3 < nvalid) *(float4*)&h[(size_t)(row0 + r0 + 3) * C + c0] = acc3;
        }
        float4 asv = *(const float4*)&a_src[c0];
        float4 adv = *(const float4*)&a_dst[c0];
        float vs0 = acc0.x*asv.x + acc0.y*asv.y + acc0.z*asv.z + acc0.w*asv.w;
        float vs1 = acc1.x*asv.x + acc1.y*asv.y + acc1.z*asv.z + acc1.w*asv.w;
        float vs2 = acc2.x*asv.x + acc2.y*asv.y + acc2.z*asv.z + acc2.w*asv.w;
        float vs3 = acc3.x*asv.x + acc3.y*asv.y + acc3.z*asv.z + acc3.w*asv.w;
        float vd0 = acc0.x*adv.x + acc0.y*adv.y + acc0.z*adv.z + acc0.w*adv.w;
        float vd1 = acc1.x*adv.x + acc1.y*adv.y + acc1.z*adv.z + acc1.w*adv.w;
        float vd2 = acc2.x*adv.x + acc2.y*adv.y + acc2.z*adv.z + acc2.w*adv.w;
        float vd3 = acc3.x*adv.x + acc3.y*adv.y + acc3.z*adv.z + acc3.w*adv.w;
#pragma unroll
        for (int off = 1; off < 16; off <<= 1) {
            vs0 += __shfl_xor(vs0, off); vs1 += __shfl_xor(vs1, off);
            vs2 += __shfl_xor(vs2, off); vs3 += __shfl_xor(vs3, off);
            vd0 += __shfl_xor(vd0, off); vd1 += __shfl_xor(vd1, off);
            vd2 += __shfl_xor(vd2, off); vd3 += __shfl_xor(vd3, off);
        }
        if (ci == 0) {
            if (r0 + 0 < nvalid) { as_[row0+r0+0] = vs0; ad_[row0+r0+0] = vd0; }
            if (r0 + 1 < nvalid) { as_[row0+r0+1] = vs1; ad_[row0+r0+1] = vd1; }
            if (r0 + 2 < nvalid) { as_[row0+r0+2] = vs2; ad_[row0+r0+2] = vd2; }
            if (r0 + 3 < nvalid) { as_[row0+r0+3] = vs3; ad_[row0+r0+3] = vd3; }
        }
    } else {                               // CPT == 1  (C = 16), fp32 h only
        float* h = (float*)hv;
        float s0 = 0.f, s1 = 0.f, s2 = 0.f, s3 = 0.f;
        for (int k = 0; k < K; k += 4) {
            float w0 = sW[(k + 0) * C + c0];
            float w1 = sW[(k + 1) * C + c0];
            float w2 = sW[(k + 2) * C + c0];
            float w3 = sW[(k + 3) * C + c0];
            float4 x0 = *(const float4*)&sx[r0 + 0][k];
            float4 x1 = *(const float4*)&sx[r0 + 1][k];
            float4 x2 = *(const float4*)&sx[r0 + 2][k];
            float4 x3 = *(const float4*)&sx[r0 + 3][k];
            s0 = fmaf(x0.x,w0, fmaf(x0.y,w1, fmaf(x0.z,w2, fmaf(x0.w,w3, s0))));
            s1 = fmaf(x1.x,w0, fmaf(x1.y,w1, fmaf(x1.z,w2, fmaf(x1.w,w3, s1))));
            s2 = fmaf(x2.x,w0, fmaf(x2.y,w1, fmaf(x2.z,w2, fmaf(x2.w,w3, s2))));
            s3 = fmaf(x3.x,w0, fmaf(x3.y,w1, fmaf(x3.z,w2, fmaf(x3.w,w3, s3))));
        }
        if (r0 + 0 < nvalid) h[(size_t)(row0+r0+0) * C + c0] = s0;
        if (r0 + 1 < nvalid) h[(size_t)(row0+r0+1) * C + c0] = s1;
        if (r0 + 2 < nvalid) h[(size_t)(row0+r0+2) * C + c0] = s2;
        if (r0 + 3 < nvalid) h[(size_t)(row0+r0+3) * C + c0] = s3;
        float as0 = a_src[c0], ad0 = a_dst[c0];
        float vs0 = s0*as0, vs1 = s1*as0, vs2 = s2*as0, vs3 = s3*as0;
        float vd0 = s0*ad0, vd1 = s1*ad0, vd2 = s2*ad0, vd3 = s3*ad0;
#pragma unroll
        for (int off = 1; off < 16; off <<= 1) {
            vs0 += __shfl_xor(vs0, off); vs1 += __shfl_xor(vs1, off);
            vs2 += __shfl_xor(vs2, off); vs3 += __shfl_xor(vs3, off);
            vd0 += __shfl_xor(vd0, off); vd1 += __shfl_xor(vd1, off);
            vd2 += __shfl_xor(vd2, off); vd3 += __shfl_xor(vd3, off);
        }
        if (ci == 0) {
            if (r0 + 0 < nvalid) { as_[row0+r0+0] = vs0; ad_[row0+r0+0] = vd0; }
            if (r0 + 1 < nvalid) { as_[row0+r0+1] = vs1; ad_[row0+r0+1] = vd1; }
            if (r0 + 2 < nvalid) { as_[row0+r0+2] = vs2; ad_[row0+r0+2] = vd2; }
            if (r0 + 3 < nvalid) { as_[row0+r0+3] = vs3; ad_[row0+r0+3] = vd3; }
        }
    }
}

// ================= fused single-pass softmax + aggregation =================
// agg64h: fp16 h table (128 B rows) -> 8 lanes/edge, 8 edge groups per wave.
// Cooperative alpha (1 exp/edge); shfl-distributed; fp32 accumulation.
// All shfls exec-uniform (stripe-rounded bounds).

__device__ __forceinline__ float leaky(float e) {
    return (e >= 0.f) ? e : 0.2f * e;
}

template<bool RELU>
__global__ __launch_bounds__(256) void agg64h(
        const __half* __restrict__ h, const float* __restrict__ as_, const float* __restrict__ ad_,
        const int* __restrict__ rowptr, const int* __restrict__ csr_src,
        const float* __restrict__ bias, float* __restrict__ out, int n)
{
    int node = (blockIdx.x * blockDim.x + threadIdx.x) >> 6;
    if (node >= n) return;
    int lane = threadIdx.x & 63;
    int g  = lane >> 3;       // edge group 0..7 (slots j = g+8k)
    int c8 = lane & 7;        // 8-channel slice (16 B of the 128 B half row)
    int start = rowptr[node], end = rowptr[node + 1];
    float adn = ad_[node];
    const char* hb = (const char*)h + (size_t)c8 * 16;

    float4 accL = {0,0,0,0}, accH = {0,0,0,0};
    float dsum = 0.f;

#define HACC(R, W) { \
    float2 f0 = __half22float2(*(__half2*)&R.x); \
    float2 f1 = __half22float2(*(__half2*)&R.y); \
    float2 f2 = __half22float2(*(__half2*)&R.z); \
    float2 f3 = __half22float2(*(__half2*)&R.w); \
    accL.x = fmaf(W, f0.x, accL.x); accL.y = fmaf(W, f0.y, accL.y); \
    accL.z = fmaf(W, f1.x, accL.z); accL.w = fmaf(W, f1.y, accL.w); \
    accH.x = fmaf(W, f2.x, accH.x); accH.y = fmaf(W, f2.y, accH.y); \
    accH.z = fmaf(W, f3.x, accH.z); accH.w = fmaf(W, f3.y, accH.w); }

    for (int chunk = start; chunk < end; chunk += 64) {
        int e_i = chunk + lane;
        int soff = 0; float aw = 0.f;
        if (e_i < end) {
            int ssrc = csr_src[e_i];                   // coalesced
            soff = ssrc << 7;                          // byte offset (128 B rows)
            aw = __expf(leaky(as_[ssrc] + adn));       // 1 exp per edge
        }
        dsum += aw;
        int nv = end - chunk; if (nv > 64) nv = 64;
        int nvu = (nv + 31) & ~31;                     // stripes of 32 slots
        for (int j = g; j < nvu; j += 32) {            // 4 gathers in flight
            int   o0 = __shfl(soff, j),      o1 = __shfl(soff, j + 8);
            int   o2 = __shfl(soff, j + 16), o3 = __shfl(soff, j + 24);
            float w0 = __shfl(aw, j),        w1 = __shfl(aw, j + 8);
            float w2 = __shfl(aw, j + 16),   w3 = __shfl(aw, j + 24);
            uint4 r0 = *(const uint4*)(hb + o0);
            uint4 r1 = *(const uint4*)(hb + o1);
            uint4 r2 = *(const uint4*)(hb + o2);
            uint4 r3 = *(const uint4*)(hb + o3);
            HACC(r0, w0) HACC(r1, w1) HACC(r2, w2) HACC(r3, w3)
        }
    }
#undef HACC
    // combine the 8 edge groups (xor lane bits 3..5)
#pragma unroll
    for (int off = 8; off <= 32; off <<= 1) {
        accL.x += __shfl_xor(accL.x, off); accL.y += __shfl_xor(accL.y, off);
        accL.z += __shfl_xor(accL.z, off); accL.w += __shfl_xor(accL.w, off);
        accH.x += __shfl_xor(accH.x, off); accH.y += __shfl_xor(accH.y, off);
        accH.z += __shfl_xor(accH.z, off); accH.w += __shfl_xor(accH.w, off);
    }
    // full-wave denom reduction
#pragma unroll
    for (int off = 1; off <= 32; off <<= 1) dsum += __shfl_xor(dsum, off);

    if (g == 0) {
        float inv = 1.f / (dsum + 1e-16f);
        float4 bl = *(const float4*)&bias[c8 * 8];
        float4 bh = *(const float4*)&bias[c8 * 8 + 4];
        float4 ol, oh;
        ol.x = fmaf(accL.x, inv, bl.x); ol.y = fmaf(accL.y, inv, bl.y);
        ol.z = fmaf(accL.z, inv, bl.z); ol.w = fmaf(accL.w, inv, bl.w);
        oh.x = fmaf(accH.x, inv, bh.x); oh.y = fmaf(accH.y, inv, bh.y);
        oh.z = fmaf(accH.z, inv, bh.z); oh.w = fmaf(accH.w, inv, bh.w);
        if (RELU) {
            ol.x = fmaxf(ol.x, 0.f); ol.y = fmaxf(ol.y, 0.f);
            ol.z = fmaxf(ol.z, 0.f); ol.w = fmaxf(ol.w, 0.f);
            oh.x = fmaxf(oh.x, 0.f); oh.y = fmaxf(oh.y, 0.f);
            oh.z = fmaxf(oh.z, 0.f); oh.w = fmaxf(oh.w, 0.f);
        }
        *(float4*)&out[(size_t)node * 64 + c8 * 8]     = ol;
        *(float4*)&out[(size_t)node * 64 + c8 * 8 + 4] = oh;
    }
}

template<bool RELU>
__global__ __launch_bounds__(256) void agg16(
        const float* __restrict__ h, const float* __restrict__ as_, const float* __restrict__ ad_,
        const int* __restrict__ rowptr, const int* __restrict__ csr_src,
        const float* __restrict__ bias, float* __restrict__ out, int n)
{
    int node = (blockIdx.x * blockDim.x + threadIdx.x) >> 6;
    if (node >= n) return;
    int lane = threadIdx.x & 63;
    int g  = lane >> 2;       // edge group 0..15 (slots j = g+16k)
    int c4 = lane & 3;        // float4 slot within 16-ch row
    int start = rowptr[node], end = rowptr[node + 1];
    float adn = ad_[node];
    const char* hb = (const char*)h + (size_t)c4 * 16;

    float4 acc = {0,0,0,0};
    float dsum = 0.f;

    for (int chunk = start; chunk < end; chunk += 64) {
        int e_i = chunk + lane;
        int soff = 0; float aw = 0.f;
        if (e_i < end) {
            int ssrc = csr_src[e_i];
            soff = ssrc << 6;                          // byte offset (64 B rows)
            aw = __expf(leaky(as_[ssrc] + adn));
        }
        dsum += aw;
        int nv = end - chunk; if (nv > 64) nv = 64;
        int nvu = (nv + 31) & ~31;                     // stripes of 32 slots
        for (int j = g; j < nvu; j += 32) {            // 2 gathers in flight
            int   o0 = __shfl(soff, j);
            int   o1 = __shfl(soff, j + 16);
            float w0 = __shfl(aw, j);
            float w1 = __shfl(aw, j + 16);
            float4 h0 = *(const float4*)(hb + o0);
            float4 h1 = *(const float4*)(hb + o1);
            acc.x = fmaf(w0, h0.x, acc.x); acc.y = fmaf(w0, h0.y, acc.y);
            acc.z = fmaf(w0, h0.z, acc.z); acc.w = fmaf(w0, h0.w, acc.w);
            acc.x = fmaf(w1, h1.x, acc.x); acc.y = fmaf(w1, h1.y, acc.y);
            acc.z = fmaf(w1, h1.z, acc.z); acc.w = fmaf(w1, h1.w, acc.w);
        }
    }
#pragma unroll
    for (int off = 4; off <= 32; off <<= 1) {
        acc.x += __shfl_xor(acc.x, off); acc.y += __shfl_xor(acc.y, off);
        acc.z += __shfl_xor(acc.z, off); acc.w += __shfl_xor(acc.w, off);
    }
#pragma unroll
    for (int off = 1; off <= 32; off <<= 1) dsum += __shfl_xor(dsum, off);

    if (g == 0) {
        float inv = 1.f / (dsum + 1e-16f);
        float4 bv = *(const float4*)&bias[c4 * 4];
        float4 o;
        o.x = fmaf(acc.x, inv, bv.x); o.y = fmaf(acc.y, inv, bv.y);
        o.z = fmaf(acc.z, inv, bv.z); o.w = fmaf(acc.w, inv, bv.w);
        if (RELU) {
            o.x = fmaxf(o.x, 0.f); o.y = fmaxf(o.y, 0.f);
            o.z = fmaxf(o.z, 0.f); o.w = fmaxf(o.w, 0.f);
        }
        *(float4*)&out[(size_t)node * 16 + c4 * 4] = o;
    }
}

// ================= launch =================

extern "C" void kernel_launch(void* const* d_in, const int* in_sizes, int n_in,
                              void* d_out, int out_size, void* d_ws, size_t ws_size,
                              hipStream_t stream) {
    const float* x   = (const float*)d_in[0];
    const int*   ei  = (const int*)  d_in[1];
    const float* W1  = (const float*)d_in[3];
    const float* as1 = (const float*)d_in[4];
    const float* ad1 = (const float*)d_in[5];
    const float* b1  = (const float*)d_in[6];
    const float* W2  = (const float*)d_in[7];
    const float* as2 = (const float*)d_in[8];
    const float* ad2 = (const float*)d_in[9];
    const float* b2  = (const float*)d_in[10];
    const float* W3  = (const float*)d_in[11];
    const float* as3 = (const float*)d_in[12];
    const float* ad3 = (const float*)d_in[13];
    const float* b3  = (const float*)d_in[14];

    const int* srcp = ei;
    const int* dstp = ei + N_EDGES;

    char* ws = (char*)d_ws;
    size_t off = 0;
    auto alloc = [&](size_t bytes) -> void* {
        void* p = ws + off;
        off = (off + bytes + 255) & ~(size_t)255;
        return p;
    };
    int*   bhist_t = (int*)  alloc((size_t)NBUCK * NBLK * sizeof(int));
    int*   btot    = (int*)  alloc(NBUCK * sizeof(int));
    int*   bbase   = (int*)  alloc((NBUCK + 1) * sizeof(int));
    int*   rowptr  = (int*)  alloc((N_NODES + 1) * sizeof(int));
    int*   csr_src = (int*)  alloc(N_EDGES * sizeof(int));
    float* asb     = (float*)alloc(N_NODES * sizeof(float));
    float* adb     = (float*)alloc(N_NODES * sizeof(float));
    __half* hHalf  = (__half*)alloc((size_t)N_NODES * 64 * sizeof(__half));
    float* bufA    = (float*)alloc((size_t)N_NODES * 64 * sizeof(float));
    float* bufB    = (float*)alloc((size_t)N_NODES * 64 * sizeof(float));
    unsigned* packed = (unsigned*)bufA;   // dead before agg1 writes bufA

    bucket_hist    <<<NBLK,  256, 0, stream>>>(dstp, bhist_t, N_EDGES);
    bucket_totals  <<<NBUCK, 256, 0, stream>>>(bhist_t, btot);
    scan_totals    <<<1,     256, 0, stream>>>(btot, bbase, rowptr);
    rewrite_offsets<<<NBUCK, 64,  0, stream>>>(bhist_t, bbase);
    bucket_scatter <<<NBLK,  256, 0, stream>>>(srcp, dstp, bhist_t, packed, N_EDGES);
    csr_finalize   <<<NBUCK, 512, 0, stream>>>(packed, bbase, rowptr, csr_src);

    const int NB64 = (N_NODES + 63) / 64;
    const int NB4  = (N_NODES + 3) / 4;

    // layer 1: 128 -> 64, relu  (h in fp16)
    gemm_alpha<128, 64, true><<<NB64, 256, 0, stream>>>(x, W1, as1, ad1, hHalf, asb, adb, N_NODES);
    agg64h<true><<<NB4, 256, 0, stream>>>(hHalf, asb, adb, rowptr, csr_src, b1, bufA, N_NODES);

    // layer 2: 64 -> 64, relu  (h in fp16)
    gemm_alpha<64, 64, true><<<NB64, 256, 0, stream>>>(bufA, W2, as2, ad2, hHalf, asb, adb, N_NODES);
    agg64h<true><<<NB4, 256, 0, stream>>>(hHalf, asb, adb, rowptr, csr_src, b2, bufA, N_NODES);

    // layer 3: 64 -> 16, no relu  (h fp32: error lands directly in output)
    gemm_alpha<64, 16, false><<<NB64, 256, 0, stream>>>(bufA, W3, as3, ad3, bufB, asb, adb, N_NODES);
    agg16<false><<<NB4, 256, 0, stream>>>(bufB, asb, adb, rowptr, csr_src, b3, (float*)d_out, N_NODES);
}